// Round 1
// baseline (1640.185 us; speedup 1.0000x reference)
//
#include <hip/hip_runtime.h>

// ComplexNetAttention on gfx950.
// Pipeline: int8-fakequant -> fused complex QKV GEMM (fp16 MFMA, NT, K=4096)
//           -> RoPE (bf16 cos/sin to match ref) -> per-head scores GEMM (fp32)
//           -> causal softmax (P fp16 in-place) -> PV GEMM -> fakequant -> out GEMM.
// All GEMMs share one template: 128x128 tile, BK=32, 256 thr (4 waves, 2x2 of
// 64x64), 4x4 MFMA 16x16x32_f16 per wave, global_load_lds width-16 staging.

typedef float v4f __attribute__((ext_vector_type(4)));
typedef _Float16 v8h __attribute__((ext_vector_type(8)));

typedef const __attribute__((address_space(1))) void glob_void;
typedef __attribute__((address_space(3))) void lds_void;

__device__ __forceinline__ void gload16(const _Float16* gp, _Float16* lp) {
  __builtin_amdgcn_global_load_lds((glob_void*)gp, (lds_void*)lp, 16, 0, 0);
}

// bf16 round-trip (RNE) in fp32 — matches reference's bf16 cos/sin cache.
__device__ __forceinline__ float bf16_rt(float f) {
  union { float f; unsigned u; } a; a.f = f;
  unsigned r = (a.u + 0x7fffu + ((a.u >> 16) & 1u)) & 0xffff0000u;
  union { unsigned u; float f; } b; b.u = r;
  return b.f;
}

#define EPI_F16   0
#define EPI_SCORE 1
#define EPI_ATTN  2
#define EPI_OUT   3

// NT GEMM: C[M][N] = A[M][K] @ B[N][K]^T, fp16 in, fp32 acc.
template<int EPI, bool SKIP_UPPER, bool CAUSAL_K>
__global__ __launch_bounds__(256) void gemm_nt(
    const _Float16* __restrict__ A, const _Float16* __restrict__ B,
    void* __restrict__ Cv, int M, int N, int K, int lda, int ldb, int ldc,
    long long aZ, long long bZ, long long cZ,
    float scale, float* __restrict__ attn, int h0)
{
  const int m0 = blockIdx.x * 128, n0 = blockIdx.y * 128;
  if (SKIP_UPPER && n0 >= m0 + 128) return;   // fully-masked causal block
  const int z = blockIdx.z;
  const _Float16* Ab = A + (long long)z * aZ;
  const _Float16* Bb = B + (long long)z * bZ;
  const int kend = CAUSAL_K ? ((m0 + 128 < K) ? (m0 + 128) : K) : K;

  __shared__ __align__(16) _Float16 As[128 * 32];
  __shared__ __align__(16) _Float16 Bs[128 * 32];

  const int tid = threadIdx.x, lane = tid & 63, wave = tid >> 6;
  // staging: tile 128 rows x 32 halfs = 8KB, 2 segs x 256 thr x 16B
  const int off0 = tid * 8, off1 = 2048 + tid * 8;
  const int r0 = off0 >> 5, c0 = off0 & 31;
  const int r1 = off1 >> 5, c1 = off1 & 31;
  const _Float16* ga0 = Ab + (long long)(m0 + r0) * lda + c0;
  const _Float16* ga1 = Ab + (long long)(m0 + r1) * lda + c1;
  const _Float16* gb0 = Bb + (long long)(n0 + r0) * ldb + c0;
  const _Float16* gb1 = Bb + (long long)(n0 + r1) * ldb + c1;

  const int mr = (wave >> 1) * 64 + (lane & 15);   // + i*16
  const int nr = (wave & 1) * 64 + (lane & 15);    // + j*16
  const int ko = (lane >> 4) * 8;                  // A[m=lane&15][k=quad*8+j]

  v4f acc[4][4] = {};

  for (int k0 = 0; k0 < kend; k0 += 32) {
    gload16(ga0 + k0, As + off0);
    gload16(ga1 + k0, As + off1);
    gload16(gb0 + k0, Bs + off0);
    gload16(gb1 + k0, Bs + off1);
    __syncthreads();   // compiler drains vmcnt before s_barrier
    v8h a[4], b[4];
#pragma unroll
    for (int i = 0; i < 4; ++i) a[i] = *(const v8h*)&As[(mr + i * 16) * 32 + ko];
#pragma unroll
    for (int j = 0; j < 4; ++j) b[j] = *(const v8h*)&Bs[(nr + j * 16) * 32 + ko];
#pragma unroll
    for (int i = 0; i < 4; ++i)
#pragma unroll
      for (int j = 0; j < 4; ++j)
        acc[i][j] = __builtin_amdgcn_mfma_f32_16x16x32_f16(a[i], b[j], acc[i][j], 0, 0, 0);
    __syncthreads();
  }

  // C/D layout (m89/m91-verified): col=lane&15, row=quad*4+reg
  const int cr = (wave >> 1) * 64 + (lane >> 4) * 4;
  const int cc = (wave & 1) * 64 + (lane & 15);
#pragma unroll
  for (int i = 0; i < 4; ++i)
#pragma unroll
    for (int j = 0; j < 4; ++j)
#pragma unroll
      for (int r = 0; r < 4; ++r) {
        const int row = m0 + cr + i * 16 + r;
        const int col = n0 + cc + j * 16;
        const float v = acc[i][j][r];
        if (EPI == EPI_F16) {
          ((_Float16*)Cv)[(long long)z * cZ + (long long)row * ldc + col] = (_Float16)v;
        } else if (EPI == EPI_SCORE) {
          ((float*)Cv)[(long long)z * cZ + (long long)row * ldc + col] = v * scale;
        } else if (EPI == EPI_ATTN) {
          const int half = col >> 7, d = col & 127;
          attn[(long long)half * M * 2048 + (long long)row * 2048 + (h0 + z) * 128 + d] = v;
        } else { // EPI_OUT: split columns [yr | yi] into concatenated outputs
          float* O = (float*)Cv;
          if (col < 2048) O[(long long)row * 2048 + col] = v;
          else O[(long long)M * 2048 + (long long)row * 2048 + (col - 2048)] = v;
        }
      }
}

// per-row int8 fake-quant of two [T][rowlen] fp32 sources -> fp16 [T][2*rowlen]
__global__ __launch_bounds__(256) void quant_rows(
    const float* __restrict__ s0, const float* __restrict__ s1,
    _Float16* __restrict__ dst, int rowlen, int dld)
{
  const int t = blockIdx.x, y = blockIdx.y;
  const float* src = (y ? s1 : s0) + (long long)t * rowlen;
  const int tid = threadIdx.x, lane = tid & 63, wave = tid >> 6;
  __shared__ float rbuf[4];
  float m = 0.f;
  for (int c = tid * 4; c < rowlen; c += 1024) {
    v4f v = *(const v4f*)(src + c);
    m = fmaxf(m, fmaxf(fmaxf(fabsf(v[0]), fabsf(v[1])), fmaxf(fabsf(v[2]), fabsf(v[3]))));
  }
  for (int o = 1; o < 64; o <<= 1) m = fmaxf(m, __shfl_xor(m, o, 64));
  if (lane == 0) rbuf[wave] = m;
  __syncthreads();
  m = fmaxf(fmaxf(rbuf[0], rbuf[1]), fmaxf(rbuf[2], rbuf[3]));
  const float scale = 127.f / fmaxf(m, 1e-5f);
  _Float16* d = dst + (long long)t * dld + (long long)y * rowlen;
  for (int c = tid * 4; c < rowlen; c += 1024) {
    v4f v = *(const v4f*)(src + c);
#pragma unroll
    for (int k = 0; k < 4; ++k) {
      float q = fminf(fmaxf(rintf(v[k] * scale), -128.f), 127.f);
      d[c + k] = (_Float16)(q / scale);
    }
  }
}

// Build concatenated complex weight matrices (fp16):
// Bqkv[12288][4096]: per source pair (Wr,Wi): rows [Wr|Wi] then [Wi|-Wr]
// Bo  [4096][4096] same from (Wo_r, Wo_i)
__global__ __launch_bounds__(256) void wprep(
    const float* __restrict__ Wq_r, const float* __restrict__ Wq_i,
    const float* __restrict__ Wk_r, const float* __restrict__ Wk_i,
    const float* __restrict__ Wv_r, const float* __restrict__ Wv_i,
    const float* __restrict__ Wo_r, const float* __restrict__ Wo_i,
    _Float16* __restrict__ Bqkv, _Float16* __restrict__ Bo)
{
  long long i4 = (long long)blockIdx.x * 256 + threadIdx.x;
  if (i4 >= 16384ll * 1024) return;
  int n = (int)(i4 >> 10);
  int c = ((int)i4 & 1023) * 4;
  const float *sA, *sB; float sg; _Float16* dst; int j;
  if (n < 12288) {
    int which = n >> 11; j = n & 2047;
    switch (which) {
      case 0: sA = Wq_r; sB = Wq_i; sg =  1.f; break;
      case 1: sA = Wq_i; sB = Wq_r; sg = -1.f; break;
      case 2: sA = Wk_r; sB = Wk_i; sg =  1.f; break;
      case 3: sA = Wk_i; sB = Wk_r; sg = -1.f; break;
      case 4: sA = Wv_r; sB = Wv_i; sg =  1.f; break;
      default: sA = Wv_i; sB = Wv_r; sg = -1.f; break;
    }
    dst = Bqkv + (long long)n * 4096;
  } else {
    int n2 = n - 12288; int which = n2 >> 11; j = n2 & 2047;
    if (which == 0) { sA = Wo_r; sB = Wo_i; sg = 1.f; }
    else            { sA = Wo_i; sB = Wo_r; sg = -1.f; }
    dst = Bo + (long long)n2 * 4096;
  }
  const float mult = (c < 2048) ? 1.f : sg;
  const float* src = (c < 2048) ? (sA + (long long)j * 2048 + c)
                                : (sB + (long long)j * 2048 + (c - 2048));
  v4f v = *(const v4f*)src;
  dst += c;
  dst[0] = (_Float16)(v[0] * mult); dst[1] = (_Float16)(v[1] * mult);
  dst[2] = (_Float16)(v[2] * mult); dst[3] = (_Float16)(v[3] * mult);
}

// RoPE on q,k (bf16-rounded cos/sin, matching ref) -> qc/kc [NH][T][256] fp16
__global__ __launch_bounds__(256) void rope_kernel(
    const _Float16* __restrict__ Y, const int* __restrict__ positions,
    _Float16* __restrict__ qc, _Float16* __restrict__ kc)
{
  const int idx = blockIdx.x * 256 + threadIdx.x;  // T*128 threads
  const int t = idx >> 7, d = idx & 127;
  const float invf = (float)pow(10000.0, -(double)d / 128.0);
  const float fr = (float)positions[t] * invf;
  const double fd = (double)fr;
  const float c = bf16_rt((float)cos(fd));
  const float s = bf16_rt((float)sin(fd));
  const _Float16* y = Y + (long long)t * 12288;
#pragma unroll
  for (int h = 0; h < 16; ++h) {
    const float qr = (float)y[h * 128 + d],        qi = (float)y[2048 + h * 128 + d];
    const float kr = (float)y[4096 + h * 128 + d], ki = (float)y[6144 + h * 128 + d];
    const long long ob = ((long long)h * 2048 + t) * 256 + d;
    qc[ob]       = (_Float16)(qr * c - qi * s);
    qc[ob + 128] = (_Float16)(qi * c + qr * s);
    kc[ob]       = (_Float16)(kr * c - ki * s);
    kc[ob + 128] = (_Float16)(ki * c + kr * s);
  }
}

// V transpose: Yqkv v-part -> vt [NH][256][T] fp16 (d-major for PV B-operand)
__global__ __launch_bounds__(256) void vtrans(
    const _Float16* __restrict__ Y, _Float16* __restrict__ vt)
{
  __shared__ float tile[64][65];
  const int t0 = blockIdx.x * 64, d0 = blockIdx.y * 64, h = blockIdx.z;
  const int tx = threadIdx.x & 63, ty = threadIdx.x >> 6;
  const int dd = d0 + tx;
  const int col = (dd < 128) ? (8192 + h * 128 + dd) : (10240 + h * 128 + (dd - 128));
  for (int rr = 0; rr < 16; ++rr) {
    const int tl = ty * 16 + rr;
    tile[tx][tl] = (float)Y[(long long)(t0 + tl) * 12288 + col];
  }
  __syncthreads();
  for (int rr = 0; rr < 16; ++rr) {
    const int dl = ty * 16 + rr;
    vt[((long long)h * 256 + (d0 + dl)) * 2048 + (t0 + tx)] = (_Float16)tile[dl][tx];
  }
}

// causal softmax over row t (s<=t), writes P fp16 IN PLACE over fp32 scores
// (row stride stays 2048 fp32 = 4096 fp16), zero-padded to 128 boundary.
__global__ __launch_bounds__(256) void softmax_rows(float* __restrict__ Sbuf)
{
  __shared__ float lrow[2048];
  __shared__ float rbuf[4];
  const int t = blockIdx.x;
  float* row = Sbuf + ((long long)blockIdx.y * 2048 + t) * 2048;
  const int n = t + 1;
  const int tid = threadIdx.x, lane = tid & 63, wave = tid >> 6;
  for (int c = tid; c < n; c += 256) lrow[c] = row[c];
  __syncthreads();
  float m = -1e30f;
  for (int c = tid; c < n; c += 256) m = fmaxf(m, lrow[c]);
  for (int o = 1; o < 64; o <<= 1) m = fmaxf(m, __shfl_xor(m, o, 64));
  if (lane == 0) rbuf[wave] = m;
  __syncthreads();
  m = fmaxf(fmaxf(rbuf[0], rbuf[1]), fmaxf(rbuf[2], rbuf[3]));
  __syncthreads();
  float sum = 0.f;
  for (int c = tid; c < n; c += 256) { float e = expf(lrow[c] - m); lrow[c] = e; sum += e; }
  for (int o = 1; o < 64; o <<= 1) sum += __shfl_xor(sum, o, 64);
  if (lane == 0) rbuf[wave] = sum;
  __syncthreads();
  sum = rbuf[0] + rbuf[1] + rbuf[2] + rbuf[3];
  const float invl = 1.f / sum;
  _Float16* prow = (_Float16*)row;
  const int npad = (n + 127) & ~127;
  for (int c = tid; c < npad; c += 256)
    prow[c] = (c < n) ? (_Float16)(lrow[c] * invl) : (_Float16)0.f;
}

extern "C" void kernel_launch(void* const* d_in, const int* in_sizes, int n_in,
                              void* d_out, int out_size, void* d_ws, size_t ws_size,
                              hipStream_t stream) {
  const float* hr   = (const float*)d_in[0];
  const float* hi   = (const float*)d_in[1];
  const int*   pos  = (const int*)d_in[2];
  const float* Wq_r = (const float*)d_in[3];
  const float* Wq_i = (const float*)d_in[4];
  const float* Wk_r = (const float*)d_in[5];
  const float* Wk_i = (const float*)d_in[6];
  const float* Wv_r = (const float*)d_in[7];
  const float* Wv_i = (const float*)d_in[8];
  const float* Wo_r = (const float*)d_in[9];
  const float* Wo_i = (const float*)d_in[10];

  char* ws = (char*)d_ws;
  // layout (MB offsets); attn aliases dead Yqkv, Ac2 aliases dead Ac
  _Float16* Bqkv = (_Float16*)(ws);                    // 96MB
  _Float16* Bo   = (_Float16*)(ws + (96ll  << 20));    // 32MB
  _Float16* Ac   = (_Float16*)(ws + (128ll << 20));    // 16MB (reused as Ac2)
  _Float16* Yq   = (_Float16*)(ws + (144ll << 20));    // 48MB fp16
  float*    attn = (float*)   (ws + (144ll << 20));    // 32MB fp32 (alias)
  _Float16* qc   = (_Float16*)(ws + (192ll << 20));    // 16MB
  _Float16* kc   = (_Float16*)(ws + (208ll << 20));    // 16MB
  _Float16* vt   = (_Float16*)(ws + (224ll << 20));    // 16MB
  float*    Sbuf = (float*)   (ws + (240ll << 20));    // HG*16MB

  int HG = 16;   // heads per score-buffer pass, shrink to fit ws
  while (HG > 1 && (240ull << 20) + (size_t)HG * (16ull << 20) > ws_size) HG >>= 1;

  quant_rows<<<dim3(2048, 2), 256, 0, stream>>>(hr, hi, Ac, 2048, 4096);
  wprep<<<65536, 256, 0, stream>>>(Wq_r, Wq_i, Wk_r, Wk_i, Wv_r, Wv_i, Wo_r, Wo_i, Bqkv, Bo);
  // fused complex QKV projection: [qr|qi](2048x4096) @ Bqkv^T -> Yq (2048x12288)
  gemm_nt<EPI_F16, false, false><<<dim3(16, 96, 1), 256, 0, stream>>>(
      Ac, Bqkv, Yq, 2048, 12288, 4096, 4096, 4096, 12288, 0, 0, 0, 1.f, nullptr, 0);
  rope_kernel<<<1024, 256, 0, stream>>>(Yq, pos, qc, kc);
  vtrans<<<dim3(32, 4, 16), 256, 0, stream>>>(Yq, vt);

  for (int g = 0; g < 16 / HG; ++g) {
    const int h0 = g * HG;
    // scores: qc[h] (2048x256) @ kc[h]^T * 1/16 -> Sbuf fp32, skip masked blocks
    gemm_nt<EPI_SCORE, true, false><<<dim3(16, 16, HG), 256, 0, stream>>>(
        qc + (long long)h0 * 2048 * 256, kc + (long long)h0 * 2048 * 256, Sbuf,
        2048, 2048, 256, 256, 256, 2048,
        2048ll * 256, 2048ll * 256, 2048ll * 2048, 0.0625f, nullptr, 0);
    softmax_rows<<<dim3(2048, HG), 256, 0, stream>>>(Sbuf);
    // PV: P (fp16 in Sbuf, lda=4096) @ vt[h]^T -> attn (r|i split), causal k-end
    gemm_nt<EPI_ATTN, false, true><<<dim3(16, 2, HG), 256, 0, stream>>>(
        (const _Float16*)Sbuf, vt + (long long)h0 * 256 * 2048, nullptr,
        2048, 256, 2048, 4096, 2048, 0,
        2048ll * 2048 * 2, 256ll * 2048, 0, 1.f, attn, h0);
  }

  quant_rows<<<dim3(2048, 2), 256, 0, stream>>>(attn, attn + 2048ll * 2048, Ac, 2048, 4096);
  // output projection -> d_out = [yr (T*H) | yi (T*H)] fp32
  gemm_nt<EPI_OUT, false, false><<<dim3(16, 32, 1), 256, 0, stream>>>(
      Ac, Bo, d_out, 2048, 4096, 4096, 4096, 4096, 0, 0, 0, 0, 1.f, nullptr, 0);
}